// Round 4
// baseline (2150.507 us; speedup 1.0000x reference)
//
#include <hip/hip_runtime.h>
#include <cstdint>
#include <cstddef>

// Problem constants
#define NB 2
#define NT 8192
#define ND 1024
#define NH 4
#define NQK 512
#define NV 1024
#define NHK 128
#define NHV 256
#define CHK 64
#define BLKT 256
#define NBLK 32
#define SCALE 0.08838834764831845f   // HK^-0.5

using f32x4 = __attribute__((ext_vector_type(4))) float;
using short8 = __attribute__((ext_vector_type(8))) short;

__device__ __forceinline__ float bf2f(unsigned short u){
  union { unsigned int i; float f; } t; t.i = ((unsigned int)u) << 16; return t.f;
}
__device__ __forceinline__ unsigned short f2bf(float f){
  union { float f; unsigned int i; } t; t.f = f;
  unsigned int r = t.i + 0x7fffu + ((t.i >> 16) & 1u);
  return (unsigned short)(r >> 16);
}
__device__ __forceinline__ void stv(float* p, float v){ *p = v; }
__device__ __forceinline__ void stv(unsigned short* p, float v){ *p = f2bf(v); }

__device__ __forceinline__ double shfl_up_dbl(double v, int off){
  union { double d; unsigned int u[2]; } a, r;
  a.d = v;
  r.u[0] = __shfl_up(a.u[0], off, 64);
  r.u[1] = __shfl_up(a.u[1], off, 64);
  return r.d;
}

// ---------------- weight transpose+cast (single): dst[c][r] = bf16(src[r][c]) ----------------
__global__ __launch_bounds__(256) void k_tc(const float* __restrict__ src,
                                            unsigned short* __restrict__ dst, int R, int C){
  int idx = blockIdx.x*256 + threadIdx.x;
  if (idx >= R*C) return;
  int r = idx % R, c = idx / R;
  dst[(size_t)c*R + r] = f2bf(src[(size_t)r*C + c]);
}

// ---------------- weight transpose+cast hi/lo pair ----------------
__global__ __launch_bounds__(256) void k_tc2(const float* __restrict__ src,
                                             unsigned short* __restrict__ dh,
                                             unsigned short* __restrict__ dl, int R, int C){
  int idx = blockIdx.x*256 + threadIdx.x;
  if (idx >= R*C) return;
  int r = idx % R, c = idx / R;
  float x = src[(size_t)r*C + c];
  unsigned short h = f2bf(x);
  unsigned short l = f2bf(x - bf2f(h));
  dh[(size_t)c*R + r] = h;
  dl[(size_t)c*R + r] = l;
}

// ---------------- high-precision GEMM: C = A(fp32)[M][K] @ Bt[N][K]^T, A split hi/lo in-register ----
// BSPLIT=1 adds the ah*bl pass (near-fp32); BSPLIT=0 keeps single-bf16 B.
template<int BSPLIT>
__global__ __launch_bounds__(256) void k_gemmA32(const float* __restrict__ A,
                                                 const unsigned short* __restrict__ Bth,
                                                 const unsigned short* __restrict__ Btl,
                                                 unsigned short* __restrict__ C, int M, int N, int K){
  __shared__ unsigned short Ah[128][40];
  __shared__ unsigned short Al[128][40];
  __shared__ unsigned short Bh[128][40];
  __shared__ unsigned short Bl[128][40];
  int tid = threadIdx.x, lane = tid & 63, wave = tid >> 6;
  int m0 = blockIdx.x*128, n0 = blockIdx.y*128;
  int wr = (wave>>1)*64, wc = (wave&1)*64;
  int row = lane & 15, kq = (lane>>4)*8;
  f32x4 acc[4][4];
  #pragma unroll
  for (int m=0;m<4;m++)
    #pragma unroll
    for (int n=0;n<4;n++)
      #pragma unroll
      for (int r=0;r<4;r++) acc[m][n][r] = 0.f;

  for (int k0=0;k0<K;k0+=32){
    __syncthreads();
    #pragma unroll
    for (int it=0; it<2; ++it){
      int s = tid + it*256;
      int r = s>>2, cb = (s&3)*8;
      f32x4 x0 = *(const f32x4*)(A + (size_t)(m0+r)*K + k0 + cb);
      f32x4 x1 = *(const f32x4*)(A + (size_t)(m0+r)*K + k0 + cb + 4);
      short8 h8, l8;
      #pragma unroll
      for (int e=0;e<4;e++){
        unsigned short h0 = f2bf(x0[e]); h8[e]   = (short)h0; l8[e]   = (short)f2bf(x0[e] - bf2f(h0));
        unsigned short h1 = f2bf(x1[e]); h8[e+4] = (short)h1; l8[e+4] = (short)f2bf(x1[e] - bf2f(h1));
      }
      *(short8*)(&Ah[r][cb]) = h8;
      *(short8*)(&Al[r][cb]) = l8;
      *(f32x4*)(&Bh[r][cb]) = *(const f32x4*)(Bth + (size_t)(n0+r)*K + k0 + cb);
      if (BSPLIT)
        *(f32x4*)(&Bl[r][cb]) = *(const f32x4*)(Btl + (size_t)(n0+r)*K + k0 + cb);
    }
    __syncthreads();
    short8 ah[4], al[4], bh[4];
    #pragma unroll
    for (int m=0;m<4;m++){ ah[m] = *(const short8*)(&Ah[wr + m*16 + row][kq]);
                           al[m] = *(const short8*)(&Al[wr + m*16 + row][kq]); }
    #pragma unroll
    for (int n=0;n<4;n++) bh[n] = *(const short8*)(&Bh[wc + n*16 + row][kq]);
    #pragma unroll
    for (int m=0;m<4;m++)
      #pragma unroll
      for (int n=0;n<4;n++){
        acc[m][n] = __builtin_amdgcn_mfma_f32_16x16x32_bf16(ah[m], bh[n], acc[m][n], 0, 0, 0);
        acc[m][n] = __builtin_amdgcn_mfma_f32_16x16x32_bf16(al[m], bh[n], acc[m][n], 0, 0, 0);
      }
    if (BSPLIT){
      short8 bl[4];
      #pragma unroll
      for (int n=0;n<4;n++) bl[n] = *(const short8*)(&Bl[wc + n*16 + row][kq]);
      #pragma unroll
      for (int m=0;m<4;m++)
        #pragma unroll
        for (int n=0;n<4;n++)
          acc[m][n] = __builtin_amdgcn_mfma_f32_16x16x32_bf16(ah[m], bl[n], acc[m][n], 0, 0, 0);
    }
  }
  #pragma unroll
  for (int m=0;m<4;m++)
    #pragma unroll
    for (int n=0;n<4;n++)
      #pragma unroll
      for (int r=0;r<4;r++){
        int rr = m0 + wr + m*16 + (lane>>4)*4 + r;
        int cc = n0 + wc + n*16 + (lane&15);
        C[(size_t)rr*N + cc] = f2bf(acc[m][n][r]);
      }
}

// ---------------- plain bf16 GEMM (final projection) ----------------
__global__ __launch_bounds__(256) void k_gemm(const unsigned short* __restrict__ A,
                                              const unsigned short* __restrict__ Bt,
                                              float* __restrict__ C, int M, int N, int K){
  __shared__ unsigned short As[128][40];
  __shared__ unsigned short Bs[128][40];
  int tid = threadIdx.x, lane = tid & 63, wave = tid >> 6;
  int m0 = blockIdx.x*128, n0 = blockIdx.y*128;
  int wr = (wave>>1)*64, wc = (wave&1)*64;
  int row = lane & 15, kq = (lane>>4)*8;
  f32x4 acc[4][4];
  #pragma unroll
  for (int m=0;m<4;m++)
    #pragma unroll
    for (int n=0;n<4;n++)
      #pragma unroll
      for (int r=0;r<4;r++) acc[m][n][r] = 0.f;

  for (int k0=0;k0<K;k0+=32){
    __syncthreads();
    #pragma unroll
    for (int it=0; it<2; ++it){
      int s = tid + it*256;
      int r = s>>2, cb = (s&3)*8;
      *(f32x4*)(&As[r][cb]) = *(const f32x4*)(A  + (size_t)(m0+r)*K + k0 + cb);
      *(f32x4*)(&Bs[r][cb]) = *(const f32x4*)(Bt + (size_t)(n0+r)*K + k0 + cb);
    }
    __syncthreads();
    short8 af[4], bfr[4];
    #pragma unroll
    for (int m=0;m<4;m++) af[m]  = *(const short8*)(&As[wr + m*16 + row][kq]);
    #pragma unroll
    for (int n=0;n<4;n++) bfr[n] = *(const short8*)(&Bs[wc + n*16 + row][kq]);
    #pragma unroll
    for (int m=0;m<4;m++)
      #pragma unroll
      for (int n=0;n<4;n++)
        acc[m][n] = __builtin_amdgcn_mfma_f32_16x16x32_bf16(af[m], bfr[n], acc[m][n], 0, 0, 0);
  }
  #pragma unroll
  for (int m=0;m<4;m++)
    #pragma unroll
    for (int n=0;n<4;n++)
      #pragma unroll
      for (int r=0;r<4;r++){
        int rr = m0 + wr + m*16 + (lane>>4)*4 + r;
        int cc = n0 + wc + n*16 + (lane&15);
        C[(size_t)rr*N + cc] = acc[m][n][r];
      }
}

// ---------------- exact fp32 alpha -> gk (pre-cumsum), layout G[(b*H+h)*T + t] ----------------
__global__ __launch_bounds__(256) void k_alpha(const float* __restrict__ hs, const float* __restrict__ Wa,
                                               const float* __restrict__ Al, const float* __restrict__ dtb,
                                               float* __restrict__ Gc){
  int rowi = blockIdx.x;
  int tid = threadIdx.x;
  const float* h = hs + (size_t)rowi*ND;
  float a0=0.f,a1=0.f,a2=0.f,a3=0.f;
  for (int d=tid; d<ND; d+=256){
    float x = h[d];
    a0 += x*Wa[d*4+0]; a1 += x*Wa[d*4+1]; a2 += x*Wa[d*4+2]; a3 += x*Wa[d*4+3];
  }
  #pragma unroll
  for (int off=32; off>0; off>>=1){
    a0 += __shfl_down(a0, off, 64); a1 += __shfl_down(a1, off, 64);
    a2 += __shfl_down(a2, off, 64); a3 += __shfl_down(a3, off, 64);
  }
  __shared__ float red[4][4];
  if ((tid&63)==0){ int w = tid>>6; red[w][0]=a0; red[w][1]=a1; red[w][2]=a2; red[w][3]=a3; }
  __syncthreads();
  if (tid < 4){
    float al = red[0][tid]+red[1][tid]+red[2][tid]+red[3][tid];
    float x = al + dtb[tid];
    float sp = (x > 20.f) ? x : log1pf(expf(x));
    float gkv = -expf(Al[tid]) * sp;
    int bb = rowi >> 13, t = rowi & (NT-1);
    Gc[((size_t)(bb*NH + tid))*NT + t] = gkv;
  }
}

// ---------------- inclusive cumsum over t in DOUBLE: Gd[bh][t] ----------------
__global__ __launch_bounds__(256) void k_cumsum(const float* __restrict__ Gc, double* __restrict__ Gd){
  int bh = blockIdx.x, tid = threadIdx.x;
  const float* g = Gc + (size_t)bh*NT;
  double* out = Gd + (size_t)bh*NT;
  __shared__ double wsum[4];
  __shared__ double carry_s;
  if (tid==0) carry_s = 0.0;
  __syncthreads();
  for (int t0=0; t0<NT; t0+=256){
    double v = (double)g[t0+tid];
    #pragma unroll
    for (int off=1; off<64; off<<=1){
      double y = shfl_up_dbl(v, off);
      if ((tid&63) >= off) v += y;
    }
    if ((tid&63)==63) wsum[tid>>6] = v;
    __syncthreads();
    double add = carry_s;
    for (int w=0; w<(tid>>6); ++w) add += wsum[w];
    v += add;
    out[t0+tid] = v;
    __syncthreads();
    if (tid==255) carry_s = v;
    __syncthreads();
  }
}

// ---------------- phase A: per-block local state (from zero) ----------------
__global__ __launch_bounds__(256) void k_phaseA(const unsigned short* __restrict__ kb,
                                                const unsigned short* __restrict__ vb,
                                                const double* __restrict__ Gd,
                                                float* __restrict__ Sb){
  int blk = blockIdx.x, bh = blockIdx.y;
  int bb = bh>>2, hh = bh&3;
  int t0 = blk*BLKT, tid = threadIdx.x;
  float Scol[128];
  #pragma unroll
  for (int kk=0;kk<128;kk++) Scol[kk] = 0.f;
  __shared__ float wk[64][128];
  __shared__ float Gsf[64];
  const double* Gb = Gd + (size_t)bh*NT;
  for (int c=0;c<4;c++){
    int cs = t0 + c*CHK;
    __syncthreads();
    if (tid < 64){
      double ref = (cs == 0) ? 0.0 : Gb[cs-1];
      Gsf[tid] = (float)(Gb[cs+tid] - ref);
    }
    __syncthreads();
    float Gend = Gsf[63];
    for (int s=tid; s<64*16; s+=256){
      int r = s>>4, cb = (s&15)*8;
      float w = expf(Gend - Gsf[r]);
      short8 kv = *(const short8*)(kb + (size_t)(bb*NT + cs + r)*NQK + hh*NHK + cb);
      f32x4 w0, w1;
      #pragma unroll
      for (int e=0;e<4;e++){
        w0[e] = w * bf2f((unsigned short)kv[e]);
        w1[e] = w * bf2f((unsigned short)kv[e+4]);
      }
      *(f32x4*)(&wk[r][cb]) = w0;
      *(f32x4*)(&wk[r][cb+4]) = w1;
    }
    __syncthreads();
    if (c > 0){
      float resc = expf(Gend);
      #pragma unroll
      for (int kk=0;kk<128;kk++) Scol[kk] *= resc;
    }
    for (int r=0;r<64;r++){
      float vval = bf2f(vb[(size_t)(bb*NT + cs + r)*NV + hh*NHV + tid]);
      #pragma unroll
      for (int p=0;p<32;p++){
        f32x4 kw = *(const f32x4*)(&wk[r][p*4]);
        #pragma unroll
        for (int e=0;e<4;e++) Scol[p*4+e] += kw[e] * vval;
      }
    }
  }
  float* dst = Sb + ((size_t)(bh*NBLK + blk))*32768 + tid;
  #pragma unroll
  for (int kk=0;kk<128;kk++) dst[kk*256] = Scol[kk];
}

// ---------------- phase B: chain block states in-place ----------------
__global__ __launch_bounds__(256) void k_phaseB(float* __restrict__ Sb, const double* __restrict__ Gd){
  int bh = blockIdx.x, tid = threadIdx.x;
  const double* Gb = Gd + (size_t)bh*NT;
  for (int blk=1; blk<NBLK; ++blk){
    float resc = expf((float)(Gb[blk*BLKT + 255] - Gb[blk*BLKT - 1]));
    const float* prev = Sb + ((size_t)(bh*NBLK + blk-1))*32768;
    float* cur        = Sb + ((size_t)(bh*NBLK + blk))*32768;
    for (int it=0; it<32; ++it){
      int f = (it*256 + tid)*4;
      f32x4 p = *(const f32x4*)(prev + f);
      f32x4 c = *(const f32x4*)(cur + f);
      #pragma unroll
      for (int e=0;e<4;e++) c[e] += resc * p[e];
      *(f32x4*)(cur + f) = c;
    }
  }
}

// ---------------- phase C (fused): intra + inter + RMSNorm + swish gate -> o2 (bf16) ----------------
__global__ __launch_bounds__(256) void k_phaseC(const unsigned short* __restrict__ qb,
                                                const unsigned short* __restrict__ kb,
                                                const unsigned short* __restrict__ vb,
                                                const unsigned short* __restrict__ gb,
                                                const float* __restrict__ rmsw,
                                                const double* __restrict__ Gd,
                                                const float* __restrict__ Sb,
                                                unsigned short* __restrict__ o2){
  int blk = blockIdx.x, bh = blockIdx.y;
  int bb = bh>>2, hh = bh&3;
  int t0 = blk*BLKT, tid = threadIdx.x;
  float rmsw_t = rmsw[tid];
  float Scol[128];
  if (blk == 0){
    #pragma unroll
    for (int kk=0;kk<128;kk++) Scol[kk] = 0.f;
  } else {
    const float* src = Sb + ((size_t)(bh*NBLK + blk-1))*32768 + tid;
    #pragma unroll
    for (int kk=0;kk<128;kk++) Scol[kk] = src[kk*256];
  }
  __shared__ unsigned short qs[64][128];
  __shared__ unsigned short ks[64][128];
  __shared__ float sc[64][64];
  __shared__ float Gsf[64];
  __shared__ float rsum[16][4];
  const double* Gb = Gd + (size_t)bh*NT;
  int lane = tid & 63, wave = tid >> 6;
  for (int c=0;c<4;c++){
    int cs = t0 + c*CHK;
    __syncthreads();
    if (tid < 64){
      double ref = (cs == 0) ? 0.0 : Gb[cs-1];
      Gsf[tid] = (float)(Gb[cs+tid] - ref);
    }
    for (int s=tid; s<64*16; s+=256){
      int r = s>>4, cb = (s&15)*8;
      size_t src = (size_t)(bb*NT + cs + r)*NQK + hh*NHK + cb;
      *(short8*)(&qs[r][cb]) = *(const short8*)(qb + src);
      *(short8*)(&ks[r][cb]) = *(const short8*)(kb + src);
    }
    __syncthreads();
    // scores
    {
      int i = tid>>2, j0 = (tid&3)*16;
      float Gi = Gsf[i];
      for (int jj=0;jj<16;jj++){
        int j = j0 + jj;
        float dot = 0.f;
        #pragma unroll
        for (int p=0;p<16;p++){
          short8 qv = *(const short8*)(&qs[i][p*8]);
          short8 kv = *(const short8*)(&ks[j][p*8]);
          #pragma unroll
          for (int e=0;e<8;e++) dot += bf2f((unsigned short)qv[e]) * bf2f((unsigned short)kv[e]);
        }
        sc[i][j] = (j <= i) ? expf(Gi - Gsf[j]) * SCALE * dot : 0.f;
      }
    }
    __syncthreads();
    float Gend = Gsf[63];
    // output rows in 4 groups of 16; thread owns column vv=tid
    for (int g4=0; g4<4; ++g4){
      int ib = g4*16;
      float o16[16];
      #pragma unroll
      for (int u=0;u<16;u++){
        float dot = 0.f;
        #pragma unroll
        for (int p=0;p<16;p++){
          short8 qv = *(const short8*)(&qs[ib+u][p*8]);
          #pragma unroll
          for (int e=0;e<8;e++) dot += bf2f((unsigned short)qv[e]) * Scol[p*8+e];
        }
        o16[u] = SCALE * expf(Gsf[ib+u]) * dot;
      }
      for (int j=0;j<64;j++){
        float vjt = bf2f(vb[(size_t)(bb*NT + cs + j)*NV + hh*NHV + tid]);
        #pragma unroll
        for (int u=0;u<16;u++) o16[u] += sc[ib+u][j] * vjt;
      }
      // fused RMSNorm (over the 256 columns = this block's threads) + swish gate
      __syncthreads();   // WAR: previous g4's rsum reads done
      #pragma unroll
      for (int u=0;u<16;u++){
        float s = o16[u]*o16[u];
        #pragma unroll
        for (int off=32; off>0; off>>=1) s += __shfl_down(s, off, 64);
        if (lane==0) rsum[u][wave] = s;
      }
      __syncthreads();
      #pragma unroll
      for (int u=0;u<16;u++){
        float ms = (rsum[u][0]+rsum[u][1]+rsum[u][2]+rsum[u][3]) * (1.f/256.f);
        float on = o16[u] * rsqrtf(ms + 1e-5f) * rmsw_t;
        size_t gidx = (size_t)(bb*NT + cs + ib + u)*NV + hh*NHV + tid;
        float gv = bf2f(gb[gidx]);
        float sw = gv / (1.f + expf(-gv));
        o2[gidx] = f2bf(on * sw);
      }
    }
    // state update to ref point Gend
    float resc = expf(Gend);
    #pragma unroll
    for (int kk=0;kk<128;kk++) Scol[kk] *= resc;
    for (int j=0;j<64;j++){
      float wv = expf(Gend - Gsf[j]) * bf2f(vb[(size_t)(bb*NT + cs + j)*NV + hh*NHV + tid]);
      #pragma unroll
      for (int p=0;p<16;p++){
        short8 kv = *(const short8*)(&ks[j][p*8]);
        #pragma unroll
        for (int e=0;e<8;e++) Scol[p*8+e] += wv * bf2f((unsigned short)kv[e]);
      }
    }
  }
}

// ---------------- launch ----------------
extern "C" void kernel_launch(void* const* d_in, const int* in_sizes, int n_in,
                              void* d_out, int out_size, void* d_ws, size_t ws_size,
                              hipStream_t stream) {
  (void)in_sizes; (void)n_in; (void)out_size;
  const float* hs  = (const float*)d_in[0];
  const float* Wq  = (const float*)d_in[1];
  const float* Wk  = (const float*)d_in[2];
  const float* Wv  = (const float*)d_in[3];
  const float* Wa  = (const float*)d_in[4];
  const float* Wg  = (const float*)d_in[5];
  const float* Wo  = (const float*)d_in[6];
  const float* Al  = (const float*)d_in[7];
  const float* dtb = (const float*)d_in[8];
  const float* rmsw= (const float*)d_in[9];
  char* ws = (char*)d_ws;

  // workspace layout — total exactly 176,947,200 B (known-safe from round 2/3)
  constexpr size_t MB = 1048576;
  constexpr size_t OFF_Q    = 0;            // 16MB bf16 q
  constexpr size_t OFF_K    = 16*MB;        // 16MB bf16 k
  constexpr size_t OFF_V    = 32*MB;        // 32MB bf16 v
  constexpr size_t OFF_G    = 64*MB;        // 32MB bf16 gate
  constexpr size_t OFF_WQH  = 96*MB;        // 1MB
  constexpr size_t OFF_WQL  = 97*MB;        // 1MB
  constexpr size_t OFF_WKH  = 98*MB;        // 1MB
  constexpr size_t OFF_WKL  = 99*MB;        // 1MB
  constexpr size_t OFF_WV   = 100*MB;       // 2MB
  constexpr size_t OFF_WG   = 102*MB;       // 2MB
  constexpr size_t OFF_GC   = 104*MB;       // 256KB fp32 pre-cumsum
  constexpr size_t OFF_GD   = 104*MB + 262144;      // 512KB double cumsum
  constexpr size_t OFF_SB   = 104*MB + 786432;      // 32MB block states; wot aliases head after phaseC
  constexpr size_t OFF_O2   = OFF_SB + 32*MB;       // 32MB bf16 o2
  constexpr size_t WS_REQUIRED = OFF_O2 + 32*MB;    // = 176,947,200
  if (ws_size < WS_REQUIRED) return;

  unsigned short* qb  = (unsigned short*)(ws + OFF_Q);
  unsigned short* kb  = (unsigned short*)(ws + OFF_K);
  unsigned short* vb  = (unsigned short*)(ws + OFF_V);
  unsigned short* gb  = (unsigned short*)(ws + OFF_G);
  unsigned short* wqh = (unsigned short*)(ws + OFF_WQH);
  unsigned short* wql = (unsigned short*)(ws + OFF_WQL);
  unsigned short* wkh = (unsigned short*)(ws + OFF_WKH);
  unsigned short* wkl = (unsigned short*)(ws + OFF_WKL);
  unsigned short* wvt = (unsigned short*)(ws + OFF_WV);
  unsigned short* wgt = (unsigned short*)(ws + OFF_WG);
  float* Gc   = (float*)(ws + OFF_GC);
  double* Gd  = (double*)(ws + OFF_GD);
  float* Sb   = (float*)(ws + OFF_SB);
  unsigned short* wot = (unsigned short*)(ws + OFF_SB);   // alias: Sb dead after phaseC
  unsigned short* o2  = (unsigned short*)(ws + OFF_O2);

  // weight transposes
  k_tc2<<<2048, 256, 0, stream>>>(Wq, wqh, wql, 1024, 512);
  k_tc2<<<2048, 256, 0, stream>>>(Wk, wkh, wkl, 1024, 512);
  k_tc <<<4096, 256, 0, stream>>>(Wv, wvt, 1024, 1024);
  k_tc <<<4096, 256, 0, stream>>>(Wg, wgt, 1024, 1024);

  // projections from fp32 hs (A split in-register); q,k also split B (3-pass)
  k_gemmA32<1><<<dim3(128,4), 256, 0, stream>>>(hs, wqh, wql, qb, 16384, 512, 1024);
  k_gemmA32<1><<<dim3(128,4), 256, 0, stream>>>(hs, wkh, wkl, kb, 16384, 512, 1024);
  k_gemmA32<0><<<dim3(128,8), 256, 0, stream>>>(hs, wvt, nullptr, vb, 16384, 1024, 1024);
  k_gemmA32<0><<<dim3(128,8), 256, 0, stream>>>(hs, wgt, nullptr, gb, 16384, 1024, 1024);

  k_alpha<<<16384, 256, 0, stream>>>(hs, Wa, Al, dtb, Gc);
  k_cumsum<<<8, 256, 0, stream>>>(Gc, Gd);

  k_phaseA<<<dim3(NBLK,8), 256, 0, stream>>>(kb, vb, Gd, Sb);
  k_phaseB<<<8, 256, 0, stream>>>(Sb, Gd);
  k_phaseC<<<dim3(NBLK,8), 256, 0, stream>>>(qb, kb, vb, gb, rmsw, Gd, Sb, o2);

  // Wo transpose into Sb alias (Sb dead now), then final GEMM
  k_tc<<<4096, 256, 0, stream>>>(Wo, wot, 1024, 1024);
  k_gemm<<<dim3(128,8), 256, 0, stream>>>(o2, wot, (float*)d_out, 16384, 1024, 1024);
}

// Round 5
// 839.934 us; speedup vs baseline: 2.5603x; 2.5603x over previous
//
#include <hip/hip_runtime.h>
#include <cstdint>
#include <cstddef>

// Problem constants
#define NB 2
#define NT 8192
#define ND 1024
#define NH 4
#define NQK 512
#define NV 1024
#define NHK 128
#define NHV 256
#define BLKT 256
#define NBLK 32
#define SCALE 0.08838834764831845f   // HK^-0.5

using f32x4 = __attribute__((ext_vector_type(4))) float;
using short8 = __attribute__((ext_vector_type(8))) short;
using s16x4 = __attribute__((ext_vector_type(4))) short;

__device__ __forceinline__ float bf2f(unsigned short u){
  union { unsigned int i; float f; } t; t.i = ((unsigned int)u) << 16; return t.f;
}
__device__ __forceinline__ unsigned short f2bf(float f){
  union { float f; unsigned int i; } t; t.f = f;
  unsigned int r = t.i + 0x7fffu + ((t.i >> 16) & 1u);
  return (unsigned short)(r >> 16);
}
__device__ __forceinline__ double shfl_up_dbl(double v, int off){
  union { double d; unsigned int u[2]; } a, r;
  a.d = v;
  r.u[0] = __shfl_up(a.u[0], off, 64);
  r.u[1] = __shfl_up(a.u[1], off, 64);
  return r.d;
}
// Swizzled LDS accessor for bf16 tiles: row-major, rowBytes in {128,256}.
// XOR byte-bits [4..6] with row&7 -> b128 fragment reads become conflict-free.
__device__ __forceinline__ void* lds_at(void* base, int row, int colElem, int rowBytes){
  return (void*)((char*)base + row*rowBytes + (((colElem*2) ^ ((row&7)<<4))));
}

// ---------------- weight transpose+cast (single): dst[c][r] = bf16(src[r][c]) ----------------
__global__ __launch_bounds__(256) void k_tc(const float* __restrict__ src,
                                            unsigned short* __restrict__ dst, int R, int C){
  int idx = blockIdx.x*256 + threadIdx.x;
  if (idx >= R*C) return;
  int r = idx % R, c = idx / R;
  dst[(size_t)c*R + r] = f2bf(src[(size_t)r*C + c]);
}

// ---------------- weight transpose+cast hi/lo pair ----------------
__global__ __launch_bounds__(256) void k_tc2(const float* __restrict__ src,
                                             unsigned short* __restrict__ dh,
                                             unsigned short* __restrict__ dl, int R, int C){
  int idx = blockIdx.x*256 + threadIdx.x;
  if (idx >= R*C) return;
  int r = idx % R, c = idx / R;
  float x = src[(size_t)r*C + c];
  unsigned short h = f2bf(x);
  unsigned short l = f2bf(x - bf2f(h));
  dh[(size_t)c*R + r] = h;
  dl[(size_t)c*R + r] = l;
}

// ---------------- high-precision GEMM: C = A(fp32)[M][K] @ Bt[N][K]^T, A split hi/lo in-register ----
template<int BSPLIT>
__global__ __launch_bounds__(256) void k_gemmA32(const float* __restrict__ A,
                                                 const unsigned short* __restrict__ Bth,
                                                 const unsigned short* __restrict__ Btl,
                                                 unsigned short* __restrict__ C, int M, int N, int K){
  __shared__ unsigned short Ah[128][40];
  __shared__ unsigned short Al[128][40];
  __shared__ unsigned short Bh[128][40];
  __shared__ unsigned short Bl[128][40];
  int tid = threadIdx.x, lane = tid & 63, wave = tid >> 6;
  int m0 = blockIdx.x*128, n0 = blockIdx.y*128;
  int wr = (wave>>1)*64, wc = (wave&1)*64;
  int row = lane & 15, kq = (lane>>4)*8;
  f32x4 acc[4][4];
  #pragma unroll
  for (int m=0;m<4;m++)
    #pragma unroll
    for (int n=0;n<4;n++)
      #pragma unroll
      for (int r=0;r<4;r++) acc[m][n][r] = 0.f;

  for (int k0=0;k0<K;k0+=32){
    __syncthreads();
    #pragma unroll
    for (int it=0; it<2; ++it){
      int s = tid + it*256;
      int r = s>>2, cb = (s&3)*8;
      f32x4 x0 = *(const f32x4*)(A + (size_t)(m0+r)*K + k0 + cb);
      f32x4 x1 = *(const f32x4*)(A + (size_t)(m0+r)*K + k0 + cb + 4);
      short8 h8, l8;
      #pragma unroll
      for (int e=0;e<4;e++){
        unsigned short h0 = f2bf(x0[e]); h8[e]   = (short)h0; l8[e]   = (short)f2bf(x0[e] - bf2f(h0));
        unsigned short h1 = f2bf(x1[e]); h8[e+4] = (short)h1; l8[e+4] = (short)f2bf(x1[e] - bf2f(h1));
      }
      *(short8*)(&Ah[r][cb]) = h8;
      *(short8*)(&Al[r][cb]) = l8;
      *(f32x4*)(&Bh[r][cb]) = *(const f32x4*)(Bth + (size_t)(n0+r)*K + k0 + cb);
      if (BSPLIT)
        *(f32x4*)(&Bl[r][cb]) = *(const f32x4*)(Btl + (size_t)(n0+r)*K + k0 + cb);
    }
    __syncthreads();
    short8 ah[4], al[4], bh[4];
    #pragma unroll
    for (int m=0;m<4;m++){ ah[m] = *(const short8*)(&Ah[wr + m*16 + row][kq]);
                           al[m] = *(const short8*)(&Al[wr + m*16 + row][kq]); }
    #pragma unroll
    for (int n=0;n<4;n++) bh[n] = *(const short8*)(&Bh[wc + n*16 + row][kq]);
    #pragma unroll
    for (int m=0;m<4;m++)
      #pragma unroll
      for (int n=0;n<4;n++){
        acc[m][n] = __builtin_amdgcn_mfma_f32_16x16x32_bf16(ah[m], bh[n], acc[m][n], 0, 0, 0);
        acc[m][n] = __builtin_amdgcn_mfma_f32_16x16x32_bf16(al[m], bh[n], acc[m][n], 0, 0, 0);
      }
    if (BSPLIT){
      short8 bl[4];
      #pragma unroll
      for (int n=0;n<4;n++) bl[n] = *(const short8*)(&Bl[wc + n*16 + row][kq]);
      #pragma unroll
      for (int m=0;m<4;m++)
        #pragma unroll
        for (int n=0;n<4;n++)
          acc[m][n] = __builtin_amdgcn_mfma_f32_16x16x32_bf16(ah[m], bl[n], acc[m][n], 0, 0, 0);
    }
  }
  #pragma unroll
  for (int m=0;m<4;m++)
    #pragma unroll
    for (int n=0;n<4;n++)
      #pragma unroll
      for (int r=0;r<4;r++){
        int rr = m0 + wr + m*16 + (lane>>4)*4 + r;
        int cc = n0 + wc + n*16 + (lane&15);
        C[(size_t)rr*N + cc] = f2bf(acc[m][n][r]);
      }
}

// ---------------- plain bf16 GEMM (final projection, fp32 out) ----------------
__global__ __launch_bounds__(256) void k_gemm(const unsigned short* __restrict__ A,
                                              const unsigned short* __restrict__ Bt,
                                              float* __restrict__ C, int M, int N, int K){
  __shared__ unsigned short As[128][40];
  __shared__ unsigned short Bs[128][40];
  int tid = threadIdx.x, lane = tid & 63, wave = tid >> 6;
  int m0 = blockIdx.x*128, n0 = blockIdx.y*128;
  int wr = (wave>>1)*64, wc = (wave&1)*64;
  int row = lane & 15, kq = (lane>>4)*8;
  f32x4 acc[4][4];
  #pragma unroll
  for (int m=0;m<4;m++)
    #pragma unroll
    for (int n=0;n<4;n++)
      #pragma unroll
      for (int r=0;r<4;r++) acc[m][n][r] = 0.f;

  for (int k0=0;k0<K;k0+=32){
    __syncthreads();
    #pragma unroll
    for (int it=0; it<2; ++it){
      int s = tid + it*256;
      int r = s>>2, cb = (s&3)*8;
      *(f32x4*)(&As[r][cb]) = *(const f32x4*)(A  + (size_t)(m0+r)*K + k0 + cb);
      *(f32x4*)(&Bs[r][cb]) = *(const f32x4*)(Bt + (size_t)(n0+r)*K + k0 + cb);
    }
    __syncthreads();
    short8 af[4], bfr[4];
    #pragma unroll
    for (int m=0;m<4;m++) af[m]  = *(const short8*)(&As[wr + m*16 + row][kq]);
    #pragma unroll
    for (int n=0;n<4;n++) bfr[n] = *(const short8*)(&Bs[wc + n*16 + row][kq]);
    #pragma unroll
    for (int m=0;m<4;m++)
      #pragma unroll
      for (int n=0;n<4;n++)
        acc[m][n] = __builtin_amdgcn_mfma_f32_16x16x32_bf16(af[m], bfr[n], acc[m][n], 0, 0, 0);
  }
  #pragma unroll
  for (int m=0;m<4;m++)
    #pragma unroll
    for (int n=0;n<4;n++)
      #pragma unroll
      for (int r=0;r<4;r++){
        int rr = m0 + wr + m*16 + (lane>>4)*4 + r;
        int cc = n0 + wc + n*16 + (lane&15);
        C[(size_t)rr*N + cc] = acc[m][n][r];
      }
}

// ---------------- exact fp32 alpha -> gk (pre-cumsum), layout G[(b*H+h)*T + t] ----------------
__global__ __launch_bounds__(256) void k_alpha(const float* __restrict__ hs, const float* __restrict__ Wa,
                                               const float* __restrict__ Al, const float* __restrict__ dtb,
                                               float* __restrict__ Gc){
  int rowi = blockIdx.x;
  int tid = threadIdx.x;
  const float* h = hs + (size_t)rowi*ND;
  float a0=0.f,a1=0.f,a2=0.f,a3=0.f;
  for (int d=tid; d<ND; d+=256){
    float x = h[d];
    a0 += x*Wa[d*4+0]; a1 += x*Wa[d*4+1]; a2 += x*Wa[d*4+2]; a3 += x*Wa[d*4+3];
  }
  #pragma unroll
  for (int off=32; off>0; off>>=1){
    a0 += __shfl_down(a0, off, 64); a1 += __shfl_down(a1, off, 64);
    a2 += __shfl_down(a2, off, 64); a3 += __shfl_down(a3, off, 64);
  }
  __shared__ float red[4][4];
  if ((tid&63)==0){ int w = tid>>6; red[w][0]=a0; red[w][1]=a1; red[w][2]=a2; red[w][3]=a3; }
  __syncthreads();
  if (tid < 4){
    float al = red[0][tid]+red[1][tid]+red[2][tid]+red[3][tid];
    float x = al + dtb[tid];
    float sp = (x > 20.f) ? x : log1pf(expf(x));
    float gkv = -expf(Al[tid]) * sp;
    int bb = rowi >> 13, t = rowi & (NT-1);
    Gc[((size_t)(bb*NH + tid))*NT + t] = gkv;
  }
}

// ---------------- inclusive cumsum over t in DOUBLE: Gd[bh][t] ----------------
__global__ __launch_bounds__(256) void k_cumsum(const float* __restrict__ Gc, double* __restrict__ Gd){
  int bh = blockIdx.x, tid = threadIdx.x;
  const float* g = Gc + (size_t)bh*NT;
  double* out = Gd + (size_t)bh*NT;
  __shared__ double wsum[4];
  __shared__ double carry_s;
  if (tid==0) carry_s = 0.0;
  __syncthreads();
  for (int t0=0; t0<NT; t0+=256){
    double v = (double)g[t0+tid];
    #pragma unroll
    for (int off=1; off<64; off<<=1){
      double y = shfl_up_dbl(v, off);
      if ((tid&63) >= off) v += y;
    }
    if ((tid&63)==63) wsum[tid>>6] = v;
    __syncthreads();
    double add = carry_s;
    for (int w=0; w<(tid>>6); ++w) add += wsum[w];
    v += add;
    out[t0+tid] = v;
    __syncthreads();
    if (tid==255) carry_s = v;
    __syncthreads();
  }
}

// ---------------- phase A (MFMA): per-block local state S^T[n][k] = sum_j exp(Gend-Gj) v_j k_j ----
__global__ __launch_bounds__(256) void k_phaseA(const unsigned short* __restrict__ kb,
                                                const unsigned short* __restrict__ vb,
                                                const double* __restrict__ Gd,
                                                float* __restrict__ Sb){
  __shared__ unsigned short vT[16384];   // [256 n][64 j] swizzled
  __shared__ unsigned short wkT[8192];   // [128 k][64 j] swizzled
  int blk = blockIdx.x, bh = blockIdx.y;
  int bb = bh>>2, hh = bh&3;
  int t0 = blk*BLKT, tid = threadIdx.x;
  int lane = tid & 63, w = tid >> 6;
  const double* Gb = Gd + (size_t)bh*NT;
  double Gend = Gb[t0+255];
  f32x4 sa[32];
  #pragma unroll
  for (int i=0;i<32;i++) sa[i] = (f32x4){0.f,0.f,0.f,0.f};
  for (int jc=0;jc<4;jc++){
    int jsg = t0 + jc*64;
    __syncthreads();
    #pragma unroll
    for (int it=0; it<8; ++it){
      int task = it*256 + tid;
      int j = task & 63, ng = task >> 6;
      short8 vv = *(const short8*)(vb + (size_t)(bb*NT + jsg + j)*NV + hh*NHV + ng*8);
      #pragma unroll
      for (int e=0;e<8;e++)
        *(unsigned short*)lds_at(vT, ng*8+e, j, 128) = (unsigned short)vv[e];
    }
    #pragma unroll
    for (int it=0; it<4; ++it){
      int task = it*256 + tid;
      int j = task & 63, kg = task >> 6;
      float wj = expf((float)(Gend - Gb[jsg + j]));
      short8 kv = *(const short8*)(kb + (size_t)(bb*NT + jsg + j)*NQK + hh*NHK + kg*8);
      #pragma unroll
      for (int e=0;e<8;e++)
        *(unsigned short*)lds_at(wkT, kg*8+e, j, 128) = f2bf(wj * bf2f((unsigned short)kv[e]));
    }
    __syncthreads();
    short8 wa[2][2];
    #pragma unroll
    for (int mt=0;mt<2;mt++)
      #pragma unroll
      for (int kk=0;kk<2;kk++)
        wa[mt][kk] = *(short8*)lds_at(wkT, 32*w + mt*16 + (lane&15), kk*32 + (lane>>4)*8, 128);
    #pragma unroll
    for (int mt=0;mt<2;mt++)
      #pragma unroll
      for (int nt=0;nt<16;nt++)
        #pragma unroll
        for (int kk=0;kk<2;kk++){
          short8 b = *(short8*)lds_at(vT, nt*16 + (lane&15), kk*32 + (lane>>4)*8, 128);
          sa[mt*16+nt] = __builtin_amdgcn_mfma_f32_16x16x32_bf16(wa[mt][kk], b, sa[mt*16+nt], 0,0,0);
        }
  }
  float* dst = Sb + (size_t)(bh*NBLK + blk)*32768;  // layout [n][k] (transposed)
  #pragma unroll
  for (int mt=0;mt<2;mt++)
    #pragma unroll
    for (int nt=0;nt<16;nt++)
      #pragma unroll
      for (int r=0;r<4;r++){
        int k = 32*w + mt*16 + (lane>>4)*4 + r;
        int n = nt*16 + (lane&15);
        dst[(size_t)n*128 + k] = sa[mt*16+nt][r];
      }
}

// ---------------- phase B: chain block states in-place (layout-agnostic, elementwise) ----------------
__global__ __launch_bounds__(256) void k_phaseB(float* __restrict__ Sb, const double* __restrict__ Gd){
  int bh = blockIdx.x, tid = threadIdx.x;
  const double* Gb = Gd + (size_t)bh*NT;
  for (int blk=1; blk<NBLK; ++blk){
    float resc = expf((float)(Gb[blk*BLKT + 255] - Gb[blk*BLKT - 1]));
    const float* prev = Sb + ((size_t)(bh*NBLK + blk-1))*32768;
    float* cur        = Sb + ((size_t)(bh*NBLK + blk))*32768;
    for (int it=0; it<32; ++it){
      int f = (it*256 + tid)*4;
      f32x4 p = *(const f32x4*)(prev + f);
      f32x4 c = *(const f32x4*)(cur + f);
      #pragma unroll
      for (int e=0;e<4;e++) c[e] += resc * p[e];
      *(f32x4*)(cur + f) = c;
    }
  }
}

// ---------------- phase C (MFMA): block-causal P@V + qg@S0^T + fused RMSNorm/gate -> o2 ----------
__global__ __launch_bounds__(256) void k_phaseC(const unsigned short* __restrict__ qb,
                                                const unsigned short* __restrict__ kb,
                                                const unsigned short* __restrict__ vb,
                                                const unsigned short* __restrict__ gb,
                                                const float* __restrict__ rmsw,
                                                const double* __restrict__ Gd,
                                                const float* __restrict__ Sb,
                                                unsigned short* __restrict__ o2){
  extern __shared__ char smem[];
  unsigned short* qs  = (unsigned short*)smem;   // [64][128] raw q (swz)
  unsigned short* ks  = qs + 8192;               // [64][128] raw k (swz)
  unsigned short* vT  = ks + 8192;               // [256][64]  (swz)
  unsigned short* STl = vT + 16384;              // [256][128] bf16 S^T (swz)
  unsigned short* scp = STl + 32768;             // [64][64] weighted scores (swz)
  float* Gsf   = (float*)(scp + 4096);           // [256]
  float* rms_s = Gsf + 256;                      // [256]
  int blk = blockIdx.x, bh = blockIdx.y;
  int bb = bh>>2, hh = bh&3;
  int t0 = blk*BLKT, tid = threadIdx.x;
  int lane = tid&63, w = tid>>6;
  const double* Gb = Gd + (size_t)bh*NT;
  {
    double ref = (t0==0) ? 0.0 : Gb[t0-1];
    Gsf[tid] = (float)(Gb[t0+tid] - ref);
    rms_s[tid] = rmsw[tid];
  }
  if (blk == 0){
    #pragma unroll
    for (int it=0; it<32; ++it){
      int idx = it*256 + tid;
      int n = idx >> 5, k4 = (idx & 31)*4;
      s16x4 z = (s16x4){0,0,0,0};
      *(s16x4*)lds_at(STl, n, k4, 256) = z;
    }
  } else {
    const float* src = Sb + (size_t)(bh*NBLK + blk - 1)*32768;
    #pragma unroll
    for (int it=0; it<32; ++it){
      int idx = it*256 + tid;
      int n = idx >> 5, k4 = (idx & 31)*4;
      f32x4 x = *(const f32x4*)(src + (size_t)n*128 + k4);
      s16x4 p;
      #pragma unroll
      for (int e=0;e<4;e++) p[e] = (short)f2bf(x[e]);
      *(s16x4*)lds_at(STl, n, k4, 256) = p;
    }
  }
  __syncthreads();
  int irow = 16*w + (lane&15);
  for (int c=0;c<4;c++){
    int csl = c*64;
    int csg = t0 + csl;
    if (c > 0) __syncthreads();
    // stage raw q chunk
    #pragma unroll
    for (int it=0; it<4; ++it){
      int task = it*256 + tid;
      int r = task >> 4, cg = (task & 15)*8;
      *(short8*)lds_at(qs, r, cg, 256) =
          *(const short8*)(qb + (size_t)(bb*NT + csg + r)*NQK + hh*NHK + cg);
    }
    __syncthreads();
    // A-fragments: raw q (for P) and qg = SCALE*exp(Gsf_i)*q (for o_inter)
    short8 qaraw[4], qag[4];
    float si = SCALE * expf(Gsf[csl + irow]);
    #pragma unroll
    for (int kk=0;kk<4;kk++){
      short8 a = *(short8*)lds_at(qs, irow, kk*32 + (lane>>4)*8, 256);
      qaraw[kk] = a;
      short8 g;
      #pragma unroll
      for (int e=0;e<8;e++) g[e] = (short)f2bf(si * bf2f((unsigned short)a[e]));
      qag[kk] = g;
    }
    // o_inter: o = qg @ ST^T  (K=128)
    f32x4 oa[16];
    #pragma unroll
    for (int nt=0;nt<16;nt++) oa[nt] = (f32x4){0.f,0.f,0.f,0.f};
    #pragma unroll
    for (int nt=0;nt<16;nt++)
      #pragma unroll
      for (int kk=0;kk<4;kk++){
        short8 b = *(short8*)lds_at(STl, nt*16 + (lane&15), kk*32 + (lane>>4)*8, 256);
        oa[nt] = __builtin_amdgcn_mfma_f32_16x16x32_bf16(qag[kk], b, oa[nt], 0,0,0);
      }
    // intra: all j-chunks <= c within the block
    for (int jc=0; jc<=c; ++jc){
      int jsl = jc*64, jsg = t0 + jsl;
      __syncthreads();   // protect ks/vT overwrite
      #pragma unroll
      for (int it=0; it<4; ++it){
        int task = it*256 + tid;
        int r = task >> 4, cg = (task & 15)*8;
        *(short8*)lds_at(ks, r, cg, 256) =
            *(const short8*)(kb + (size_t)(bb*NT + jsg + r)*NQK + hh*NHK + cg);
      }
      #pragma unroll
      for (int it=0; it<8; ++it){
        int task = it*256 + tid;
        int j = task & 63, ng = task >> 6;
        short8 vv = *(const short8*)(vb + (size_t)(bb*NT + jsg + j)*NV + hh*NHV + ng*8);
        #pragma unroll
        for (int e=0;e<8;e++)
          *(unsigned short*)lds_at(vT, ng*8+e, j, 128) = (unsigned short)vv[e];
      }
      __syncthreads();
      // P = q @ k^T (K=128)
      f32x4 pa[4];
      #pragma unroll
      for (int jt=0;jt<4;jt++) pa[jt] = (f32x4){0.f,0.f,0.f,0.f};
      #pragma unroll
      for (int jt=0;jt<4;jt++)
        #pragma unroll
        for (int kk=0;kk<4;kk++){
          short8 b = *(short8*)lds_at(ks, jt*16 + (lane&15), kk*32 + (lane>>4)*8, 256);
          pa[jt] = __builtin_amdgcn_mfma_f32_16x16x32_bf16(qaraw[kk], b, pa[jt], 0,0,0);
        }
      // decay weight + causal mask on fragments -> scp (bf16)
      #pragma unroll
      for (int jt=0;jt<4;jt++)
        #pragma unroll
        for (int r=0;r<4;r++){
          int il = csl + 16*w + (lane>>4)*4 + r;
          int jl = jsl + jt*16 + (lane&15);
          float wgt = (jl <= il) ? SCALE * expf(Gsf[il] - Gsf[jl]) : 0.f;
          *(unsigned short*)lds_at(scp, 16*w + (lane>>4)*4 + r, jt*16 + (lane&15), 128)
              = f2bf(wgt * pa[jt][r]);
        }
      __syncthreads();
      // o += scp @ vT^T (K=64)
      short8 sa2[2];
      #pragma unroll
      for (int kk=0;kk<2;kk++)
        sa2[kk] = *(short8*)lds_at(scp, irow, kk*32 + (lane>>4)*8, 128);
      #pragma unroll
      for (int nt=0;nt<16;nt++)
        #pragma unroll
        for (int kk=0;kk<2;kk++){
          short8 b = *(short8*)lds_at(vT, nt*16 + (lane&15), kk*32 + (lane>>4)*8, 128);
          oa[nt] = __builtin_amdgcn_mfma_f32_16x16x32_bf16(sa2[kk], b, oa[nt], 0,0,0);
        }
    }
    // epilogue: RMSNorm over n (256 cols, wave-owned) + swish gate, write o2
    float p4[4] = {0.f,0.f,0.f,0.f};
    #pragma unroll
    for (int nt=0;nt<16;nt++)
      #pragma unroll
      for (int r=0;r<4;r++) p4[r] += oa[nt][r]*oa[nt][r];
    #pragma unroll
    for (int r=0;r<4;r++){
      #pragma unroll
      for (int off=1; off<16; off<<=1) p4[r] += __shfl_xor(p4[r], off, 16);
    }
    float fr[4];
    #pragma unroll
    for (int r=0;r<4;r++) fr[r] = rsqrtf(p4[r]*(1.f/256.f) + 1e-5f);
    #pragma unroll
    for (int nt=0;nt<16;nt++)
      #pragma unroll
      for (int r=0;r<4;r++){
        int tg = csg + 16*w + (lane>>4)*4 + r;
        int n = nt*16 + (lane&15);
        size_t gidx = (size_t)(bb*NT + tg)*NV + hh*NHV + n;
        float gv = bf2f(gb[gidx]);
        float sw = gv / (1.f + expf(-gv));
        o2[gidx] = f2bf(oa[nt][r] * fr[r] * rms_s[n] * sw);
      }
  }
}

// ---------------- launch ----------------
extern "C" void kernel_launch(void* const* d_in, const int* in_sizes, int n_in,
                              void* d_out, int out_size, void* d_ws, size_t ws_size,
                              hipStream_t stream) {
  (void)in_sizes; (void)n_in; (void)out_size;
  const float* hs  = (const float*)d_in[0];
  const float* Wq  = (const float*)d_in[1];
  const float* Wk  = (const float*)d_in[2];
  const float* Wv  = (const float*)d_in[3];
  const float* Wa  = (const float*)d_in[4];
  const float* Wg  = (const float*)d_in[5];
  const float* Wo  = (const float*)d_in[6];
  const float* Al  = (const float*)d_in[7];
  const float* dtb = (const float*)d_in[8];
  const float* rmsw= (const float*)d_in[9];
  char* ws = (char*)d_ws;

  // workspace layout — total exactly 176,947,200 B (known-safe)
  constexpr size_t MB = 1048576;
  constexpr size_t OFF_Q    = 0;            // 16MB bf16 q
  constexpr size_t OFF_K    = 16*MB;        // 16MB bf16 k
  constexpr size_t OFF_V    = 32*MB;        // 32MB bf16 v
  constexpr size_t OFF_G    = 64*MB;        // 32MB bf16 gate
  constexpr size_t OFF_WQH  = 96*MB;
  constexpr size_t OFF_WQL  = 97*MB;
  constexpr size_t OFF_WKH  = 98*MB;
  constexpr size_t OFF_WKL  = 99*MB;
  constexpr size_t OFF_WV   = 100*MB;
  constexpr size_t OFF_WG   = 102*MB;
  constexpr size_t OFF_GC   = 104*MB;
  constexpr size_t OFF_GD   = 104*MB + 262144;
  constexpr size_t OFF_SB   = 104*MB + 786432;      // 32MB S^T states; wot alias after phaseC
  constexpr size_t OFF_O2   = OFF_SB + 32*MB;       // 32MB bf16 o2
  constexpr size_t WS_REQUIRED = OFF_O2 + 32*MB;    // = 176,947,200
  if (ws_size < WS_REQUIRED) return;

  unsigned short* qb  = (unsigned short*)(ws + OFF_Q);
  unsigned short* kb  = (unsigned short*)(ws + OFF_K);
  unsigned short* vb  = (unsigned short*)(ws + OFF_V);
  unsigned short* gb  = (unsigned short*)(ws + OFF_G);
  unsigned short* wqh = (unsigned short*)(ws + OFF_WQH);
  unsigned short* wql = (unsigned short*)(ws + OFF_WQL);
  unsigned short* wkh = (unsigned short*)(ws + OFF_WKH);
  unsigned short* wkl = (unsigned short*)(ws + OFF_WKL);
  unsigned short* wvt = (unsigned short*)(ws + OFF_WV);
  unsigned short* wgt = (unsigned short*)(ws + OFF_WG);
  float* Gc   = (float*)(ws + OFF_GC);
  double* Gd  = (double*)(ws + OFF_GD);
  float* Sb   = (float*)(ws + OFF_SB);
  unsigned short* wot = (unsigned short*)(ws + OFF_SB);   // alias: Sb dead after phaseC
  unsigned short* o2  = (unsigned short*)(ws + OFF_O2);

  // weight transposes
  k_tc2<<<2048, 256, 0, stream>>>(Wq, wqh, wql, 1024, 512);
  k_tc2<<<2048, 256, 0, stream>>>(Wk, wkh, wkl, 1024, 512);
  k_tc <<<4096, 256, 0, stream>>>(Wv, wvt, 1024, 1024);
  k_tc <<<4096, 256, 0, stream>>>(Wg, wgt, 1024, 1024);

  // projections from fp32 hs
  k_gemmA32<1><<<dim3(128,4), 256, 0, stream>>>(hs, wqh, wql, qb, 16384, 512, 1024);
  k_gemmA32<1><<<dim3(128,4), 256, 0, stream>>>(hs, wkh, wkl, kb, 16384, 512, 1024);
  k_gemmA32<0><<<dim3(128,8), 256, 0, stream>>>(hs, wvt, nullptr, vb, 16384, 1024, 1024);
  k_gemmA32<0><<<dim3(128,8), 256, 0, stream>>>(hs, wgt, nullptr, gb, 16384, 1024, 1024);

  k_alpha<<<16384, 256, 0, stream>>>(hs, Wa, Al, dtb, Gc);
  k_cumsum<<<8, 256, 0, stream>>>(Gc, Gd);

  k_phaseA<<<dim3(NBLK,8), 256, 0, stream>>>(kb, vb, Gd, Sb);
  k_phaseB<<<8, 256, 0, stream>>>(Sb, Gd);

  constexpr int PHC_LDS = (8192+8192+16384+32768+4096)*2 + 256*4 + 256*4;  // 141,312 B
  hipFuncSetAttribute(reinterpret_cast<const void*>(k_phaseC),
                      hipFuncAttributeMaxDynamicSharedMemorySize, PHC_LDS);
  k_phaseC<<<dim3(NBLK,8), 256, PHC_LDS, stream>>>(qb, kb, vb, gb, rmsw, Gd, Sb, o2);

  // Wo transpose into Sb alias (Sb dead now), then final GEMM
  k_tc<<<4096, 256, 0, stream>>>(Wo, wot, 1024, 1024);
  k_gemm<<<dim3(128,8), 256, 0, stream>>>(o2, wot, (float*)d_out, 16384, 1024, 1024);
}

// Round 6
// 563.584 us; speedup vs baseline: 3.8158x; 1.4903x over previous
//
#include <hip/hip_runtime.h>
#include <cstdint>
#include <cstddef>

// Problem constants
#define NB 2
#define NT 8192
#define ND 1024
#define NH 4
#define NQK 512
#define NV 1024
#define NHK 128
#define NHV 256
#define BLKT 256
#define NBLK 32
#define SCALE 0.08838834764831845f   // HK^-0.5

using f32x4 = __attribute__((ext_vector_type(4))) float;
using short8 = __attribute__((ext_vector_type(8))) short;
using s16x4 = __attribute__((ext_vector_type(4))) short;

__device__ __forceinline__ float bf2f(unsigned short u){
  union { unsigned int i; float f; } t; t.i = ((unsigned int)u) << 16; return t.f;
}
__device__ __forceinline__ unsigned short f2bf(float f){
  union { float f; unsigned int i; } t; t.f = f;
  unsigned int r = t.i + 0x7fffu + ((t.i >> 16) & 1u);
  return (unsigned short)(r >> 16);
}
__device__ __forceinline__ double shfl_up_dbl(double v, int off){
  union { double d; unsigned int u[2]; } a, r;
  a.d = v;
  r.u[0] = __shfl_up(a.u[0], off, 64);
  r.u[1] = __shfl_up(a.u[1], off, 64);
  return r.d;
}
// Swizzled LDS accessor for bf16 tiles: row-major, rowBytes in {128,256}.
__device__ __forceinline__ void* lds_at(void* base, int row, int colElem, int rowBytes){
  return (void*)((char*)base + row*rowBytes + (((colElem*2) ^ ((row&7)<<4))));
}

// ---------------- weight transpose+cast (single): dst[c][r] = bf16(src[r][c]) ----------------
__global__ __launch_bounds__(256) void k_tc(const float* __restrict__ src,
                                            unsigned short* __restrict__ dst, int R, int C){
  int idx = blockIdx.x*256 + threadIdx.x;
  if (idx >= R*C) return;
  int r = idx % R, c = idx / R;
  dst[(size_t)c*R + r] = f2bf(src[(size_t)r*C + c]);
}

// ---------------- weight transpose+cast hi/lo pair ----------------
__global__ __launch_bounds__(256) void k_tc2(const float* __restrict__ src,
                                             unsigned short* __restrict__ dh,
                                             unsigned short* __restrict__ dl, int R, int C){
  int idx = blockIdx.x*256 + threadIdx.x;
  if (idx >= R*C) return;
  int r = idx % R, c = idx / R;
  float x = src[(size_t)r*C + c];
  unsigned short h = f2bf(x);
  unsigned short l = f2bf(x - bf2f(h));
  dh[(size_t)c*R + r] = h;
  dl[(size_t)c*R + r] = l;
}

// ---------------- split fp32 -> (hi,lo) bf16, 8 elems/thread ----------------
__global__ __launch_bounds__(256) void k_split(const float* __restrict__ s,
                                               unsigned short* __restrict__ dh,
                                               unsigned short* __restrict__ dl, int n){
  int i = (blockIdx.x*256 + threadIdx.x)*8;
  if (i >= n) return;
  f32x4 x0 = *(const f32x4*)(s+i);
  f32x4 x1 = *(const f32x4*)(s+i+4);
  short8 h8, l8;
  #pragma unroll
  for (int e=0;e<4;e++){
    unsigned short h0 = f2bf(x0[e]); h8[e]   = (short)h0; l8[e]   = (short)f2bf(x0[e] - bf2f(h0));
    unsigned short h1 = f2bf(x1[e]); h8[e+4] = (short)h1; l8[e+4] = (short)f2bf(x1[e] - bf2f(h1));
  }
  *(short8*)(dh+i) = h8;
  *(short8*)(dl+i) = l8;
}

// ------- split GEMM: C = (Ah+Al)[M][K] @ Bt^T (+ Ah@Bl^T if BSPLIT), all bf16 staged -------
template<int BSPLIT>
__global__ __launch_bounds__(256) void k_gemm2(const unsigned short* __restrict__ A2h,
                                               const unsigned short* __restrict__ A2l,
                                               const unsigned short* __restrict__ Bth,
                                               const unsigned short* __restrict__ Btl,
                                               unsigned short* __restrict__ C, int M, int N, int K){
  __shared__ unsigned short Ah[128][40];
  __shared__ unsigned short Al[128][40];
  __shared__ unsigned short Bh[128][40];
  __shared__ unsigned short Bl[128][40];
  int tid = threadIdx.x, lane = tid & 63, wave = tid >> 6;
  int m0 = blockIdx.x*128, n0 = blockIdx.y*128;
  int wr = (wave>>1)*64, wc = (wave&1)*64;
  int row = lane & 15, kq = (lane>>4)*8;
  f32x4 acc[4][4];
  #pragma unroll
  for (int m=0;m<4;m++)
    #pragma unroll
    for (int n=0;n<4;n++)
      #pragma unroll
      for (int r=0;r<4;r++) acc[m][n][r] = 0.f;

  for (int k0=0;k0<K;k0+=32){
    __syncthreads();
    #pragma unroll
    for (int it=0; it<2; ++it){
      int s = tid + it*256;
      int r = s>>2, cb = (s&3)*8;
      *(f32x4*)(&Ah[r][cb]) = *(const f32x4*)(A2h + (size_t)(m0+r)*K + k0 + cb);
      *(f32x4*)(&Al[r][cb]) = *(const f32x4*)(A2l + (size_t)(m0+r)*K + k0 + cb);
      *(f32x4*)(&Bh[r][cb]) = *(const f32x4*)(Bth + (size_t)(n0+r)*K + k0 + cb);
      if (BSPLIT)
        *(f32x4*)(&Bl[r][cb]) = *(const f32x4*)(Btl + (size_t)(n0+r)*K + k0 + cb);
    }
    __syncthreads();
    short8 ah[4], al[4], bh[4];
    #pragma unroll
    for (int m=0;m<4;m++){ ah[m] = *(const short8*)(&Ah[wr + m*16 + row][kq]);
                           al[m] = *(const short8*)(&Al[wr + m*16 + row][kq]); }
    #pragma unroll
    for (int n=0;n<4;n++) bh[n] = *(const short8*)(&Bh[wc + n*16 + row][kq]);
    #pragma unroll
    for (int m=0;m<4;m++)
      #pragma unroll
      for (int n=0;n<4;n++){
        acc[m][n] = __builtin_amdgcn_mfma_f32_16x16x32_bf16(ah[m], bh[n], acc[m][n], 0, 0, 0);
        acc[m][n] = __builtin_amdgcn_mfma_f32_16x16x32_bf16(al[m], bh[n], acc[m][n], 0, 0, 0);
      }
    if (BSPLIT){
      short8 bl[4];
      #pragma unroll
      for (int n=0;n<4;n++) bl[n] = *(const short8*)(&Bl[wc + n*16 + row][kq]);
      #pragma unroll
      for (int m=0;m<4;m++)
        #pragma unroll
        for (int n=0;n<4;n++)
          acc[m][n] = __builtin_amdgcn_mfma_f32_16x16x32_bf16(ah[m], bl[n], acc[m][n], 0, 0, 0);
    }
  }
  #pragma unroll
  for (int m=0;m<4;m++)
    #pragma unroll
    for (int n=0;n<4;n++)
      #pragma unroll
      for (int r=0;r<4;r++){
        int rr = m0 + wr + m*16 + (lane>>4)*4 + r;
        int cc = n0 + wc + n*16 + (lane&15);
        C[(size_t)rr*N + cc] = f2bf(acc[m][n][r]);
      }
}

// ---------------- plain bf16 GEMM (final projection, fp32 out) ----------------
__global__ __launch_bounds__(256) void k_gemm(const unsigned short* __restrict__ A,
                                              const unsigned short* __restrict__ Bt,
                                              float* __restrict__ C, int M, int N, int K){
  __shared__ unsigned short As[128][40];
  __shared__ unsigned short Bs[128][40];
  int tid = threadIdx.x, lane = tid & 63, wave = tid >> 6;
  int m0 = blockIdx.x*128, n0 = blockIdx.y*128;
  int wr = (wave>>1)*64, wc = (wave&1)*64;
  int row = lane & 15, kq = (lane>>4)*8;
  f32x4 acc[4][4];
  #pragma unroll
  for (int m=0;m<4;m++)
    #pragma unroll
    for (int n=0;n<4;n++)
      #pragma unroll
      for (int r=0;r<4;r++) acc[m][n][r] = 0.f;

  for (int k0=0;k0<K;k0+=32){
    __syncthreads();
    #pragma unroll
    for (int it=0; it<2; ++it){
      int s = tid + it*256;
      int r = s>>2, cb = (s&3)*8;
      *(f32x4*)(&As[r][cb]) = *(const f32x4*)(A  + (size_t)(m0+r)*K + k0 + cb);
      *(f32x4*)(&Bs[r][cb]) = *(const f32x4*)(Bt + (size_t)(n0+r)*K + k0 + cb);
    }
    __syncthreads();
    short8 af[4], bfr[4];
    #pragma unroll
    for (int m=0;m<4;m++) af[m]  = *(const short8*)(&As[wr + m*16 + row][kq]);
    #pragma unroll
    for (int n=0;n<4;n++) bfr[n] = *(const short8*)(&Bs[wc + n*16 + row][kq]);
    #pragma unroll
    for (int m=0;m<4;m++)
      #pragma unroll
      for (int n=0;n<4;n++)
        acc[m][n] = __builtin_amdgcn_mfma_f32_16x16x32_bf16(af[m], bfr[n], acc[m][n], 0, 0, 0);
  }
  #pragma unroll
  for (int m=0;m<4;m++)
    #pragma unroll
    for (int n=0;n<4;n++)
      #pragma unroll
      for (int r=0;r<4;r++){
        int rr = m0 + wr + m*16 + (lane>>4)*4 + r;
        int cc = n0 + wc + n*16 + (lane&15);
        C[(size_t)rr*N + cc] = acc[m][n][r];
      }
}

// ---------------- exact fp32 alpha -> gk (pre-cumsum), layout G[(b*H+h)*T + t] ----------------
__global__ __launch_bounds__(256) void k_alpha(const float* __restrict__ hs, const float* __restrict__ Wa,
                                               const float* __restrict__ Al, const float* __restrict__ dtb,
                                               float* __restrict__ Gc){
  int rowi = blockIdx.x;
  int tid = threadIdx.x;
  const float* h = hs + (size_t)rowi*ND;
  float a0=0.f,a1=0.f,a2=0.f,a3=0.f;
  for (int d=tid; d<ND; d+=256){
    float x = h[d];
    a0 += x*Wa[d*4+0]; a1 += x*Wa[d*4+1]; a2 += x*Wa[d*4+2]; a3 += x*Wa[d*4+3];
  }
  #pragma unroll
  for (int off=32; off>0; off>>=1){
    a0 += __shfl_down(a0, off, 64); a1 += __shfl_down(a1, off, 64);
    a2 += __shfl_down(a2, off, 64); a3 += __shfl_down(a3, off, 64);
  }
  __shared__ float red[4][4];
  if ((tid&63)==0){ int w = tid>>6; red[w][0]=a0; red[w][1]=a1; red[w][2]=a2; red[w][3]=a3; }
  __syncthreads();
  if (tid < 4){
    float al = red[0][tid]+red[1][tid]+red[2][tid]+red[3][tid];
    float x = al + dtb[tid];
    float sp = (x > 20.f) ? x : log1pf(expf(x));
    float gkv = -expf(Al[tid]) * sp;
    int bb = rowi >> 13, t = rowi & (NT-1);
    Gc[((size_t)(bb*NH + tid))*NT + t] = gkv;
  }
}

// ---------------- inclusive cumsum over t in DOUBLE: Gd[bh][t] ----------------
__global__ __launch_bounds__(256) void k_cumsum(const float* __restrict__ Gc, double* __restrict__ Gd){
  int bh = blockIdx.x, tid = threadIdx.x;
  const float* g = Gc + (size_t)bh*NT;
  double* out = Gd + (size_t)bh*NT;
  __shared__ double wsum[4];
  __shared__ double carry_s;
  if (tid==0) carry_s = 0.0;
  __syncthreads();
  for (int t0=0; t0<NT; t0+=256){
    double v = (double)g[t0+tid];
    #pragma unroll
    for (int off=1; off<64; off<<=1){
      double y = shfl_up_dbl(v, off);
      if ((tid&63) >= off) v += y;
    }
    if ((tid&63)==63) wsum[tid>>6] = v;
    __syncthreads();
    double add = carry_s;
    for (int w=0; w<(tid>>6); ++w) add += wsum[w];
    v += add;
    out[t0+tid] = v;
    __syncthreads();
    if (tid==255) carry_s = v;
    __syncthreads();
  }
}

// ---------------- phase A (MFMA): per-block local state S^T[n][k] = sum_j exp(Gend-Gj) v_j k_j ----
__global__ __launch_bounds__(256) void k_phaseA(const unsigned short* __restrict__ kb,
                                                const unsigned short* __restrict__ vb,
                                                const double* __restrict__ Gd,
                                                float* __restrict__ Sb){
  __shared__ unsigned short vT[16384];   // [256 n][64 j] swizzled
  __shared__ unsigned short wkT[8192];   // [128 k][64 j] swizzled
  int blk = blockIdx.x, bh = blockIdx.y;
  int bb = bh>>2, hh = bh&3;
  int t0 = blk*BLKT, tid = threadIdx.x;
  int lane = tid & 63, w = tid >> 6;
  const double* Gb = Gd + (size_t)bh*NT;
  double Gend = Gb[t0+255];
  f32x4 sa[32];
  #pragma unroll
  for (int i=0;i<32;i++) sa[i] = (f32x4){0.f,0.f,0.f,0.f};
  for (int jc=0;jc<4;jc++){
    int jsg = t0 + jc*64;
    __syncthreads();
    #pragma unroll
    for (int it=0; it<8; ++it){
      int task = it*256 + tid;
      int j = task & 63, ng = task >> 6;
      short8 vv = *(const short8*)(vb + (size_t)(bb*NT + jsg + j)*NV + hh*NHV + ng*8);
      #pragma unroll
      for (int e=0;e<8;e++)
        *(unsigned short*)lds_at(vT, ng*8+e, j, 128) = (unsigned short)vv[e];
    }
    #pragma unroll
    for (int it=0; it<4; ++it){
      int task = it*256 + tid;
      int j = task & 63, kg = task >> 6;
      float wj = expf((float)(Gend - Gb[jsg + j]));
      short8 kv = *(const short8*)(kb + (size_t)(bb*NT + jsg + j)*NQK + hh*NHK + kg*8);
      #pragma unroll
      for (int e=0;e<8;e++)
        *(unsigned short*)lds_at(wkT, kg*8+e, j, 128) = f2bf(wj * bf2f((unsigned short)kv[e]));
    }
    __syncthreads();
    short8 wa[2][2];
    #pragma unroll
    for (int mt=0;mt<2;mt++)
      #pragma unroll
      for (int kk=0;kk<2;kk++)
        wa[mt][kk] = *(short8*)lds_at(wkT, 32*w + mt*16 + (lane&15), kk*32 + (lane>>4)*8, 128);
    #pragma unroll
    for (int mt=0;mt<2;mt++)
      #pragma unroll
      for (int nt=0;nt<16;nt++)
        #pragma unroll
        for (int kk=0;kk<2;kk++){
          short8 b = *(short8*)lds_at(vT, nt*16 + (lane&15), kk*32 + (lane>>4)*8, 128);
          sa[mt*16+nt] = __builtin_amdgcn_mfma_f32_16x16x32_bf16(wa[mt][kk], b, sa[mt*16+nt], 0,0,0);
        }
  }
  float* dst = Sb + (size_t)(bh*NBLK + blk)*32768;  // layout [n][k] (transposed)
  #pragma unroll
  for (int mt=0;mt<2;mt++)
    #pragma unroll
    for (int nt=0;nt<16;nt++)
      #pragma unroll
      for (int r=0;r<4;r++){
        int k = 32*w + mt*16 + (lane>>4)*4 + r;
        int n = nt*16 + (lane&15);
        dst[(size_t)n*128 + k] = sa[mt*16+nt][r];
      }
}

// ---------------- phase B: parallel elementwise scan over blocks ----------------
// grid (32 slices, 8 bh); each thread owns 4 consecutive floats of the state.
__global__ __launch_bounds__(256) void k_phaseB(float* __restrict__ Sb, const double* __restrict__ Gd){
  int slice = blockIdx.x, bh = blockIdx.y;
  int tid = threadIdx.x;
  const double* Gb = Gd + (size_t)bh*NT;
  float* base = Sb + (size_t)(bh*NBLK)*32768 + slice*1024 + tid*4;
  f32x4 run = *(const f32x4*)(base);              // block 0 is already final
  f32x4 nxt = *(const f32x4*)(base + 32768);
  for (int b=1; b<NBLK; ++b){
    f32x4 cur = nxt;
    if (b+1 < NBLK) nxt = *(const f32x4*)(base + (size_t)(b+1)*32768);
    float resc = expf((float)(Gb[b*BLKT + 255] - Gb[b*BLKT - 1]));
    #pragma unroll
    for (int e=0;e<4;e++) cur[e] += resc * run[e];
    *(f32x4*)(base + (size_t)b*32768) = cur;
    run = cur;
  }
}

// ---------------- phase C (MFMA): block-causal P@V + qg@S0^T + fused RMSNorm/gate -> o2 ----------
__global__ __launch_bounds__(256) void k_phaseC(const unsigned short* __restrict__ qb,
                                                const unsigned short* __restrict__ kb,
                                                const unsigned short* __restrict__ vb,
                                                const unsigned short* __restrict__ gb,
                                                const float* __restrict__ rmsw,
                                                const double* __restrict__ Gd,
                                                const float* __restrict__ Sb,
                                                unsigned short* __restrict__ o2){
  extern __shared__ char smem[];
  unsigned short* qs  = (unsigned short*)smem;   // [64][128] raw q (swz)
  unsigned short* ks  = qs + 8192;               // [64][128] raw k (swz)
  unsigned short* vT  = ks + 8192;               // [256][64]  (swz)
  unsigned short* STl = vT + 16384;              // [256][128] bf16 S^T (swz)
  unsigned short* scp = STl + 32768;             // [64][64] weighted scores (swz)
  float* Gsf   = (float*)(scp + 4096);           // [256]
  float* rms_s = Gsf + 256;                      // [256]
  int blk = blockIdx.x, bh = blockIdx.y;
  int bb = bh>>2, hh = bh&3;
  int t0 = blk*BLKT, tid = threadIdx.x;
  int lane = tid&63, w = tid>>6;
  const double* Gb = Gd + (size_t)bh*NT;
  {
    double ref = (t0==0) ? 0.0 : Gb[t0-1];
    Gsf[tid] = (float)(Gb[t0+tid] - ref);
    rms_s[tid] = rmsw[tid];
  }
  if (blk == 0){
    #pragma unroll
    for (int it=0; it<32; ++it){
      int idx = it*256 + tid;
      int n = idx >> 5, k4 = (idx & 31)*4;
      s16x4 z = (s16x4){0,0,0,0};
      *(s16x4*)lds_at(STl, n, k4, 256) = z;
    }
  } else {
    const float* src = Sb + (size_t)(bh*NBLK + blk - 1)*32768;
    #pragma unroll
    for (int it=0; it<32; ++it){
      int idx = it*256 + tid;
      int n = idx >> 5, k4 = (idx & 31)*4;
      f32x4 x = *(const f32x4*)(src + (size_t)n*128 + k4);
      s16x4 p;
      #pragma unroll
      for (int e=0;e<4;e++) p[e] = (short)f2bf(x[e]);
      *(s16x4*)lds_at(STl, n, k4, 256) = p;
    }
  }
  __syncthreads();
  int irow = 16*w + (lane&15);
  for (int c=0;c<4;c++){
    int csl = c*64;
    int csg = t0 + csl;
    if (c > 0) __syncthreads();
    #pragma unroll
    for (int it=0; it<4; ++it){
      int task = it*256 + tid;
      int r = task >> 4, cg = (task & 15)*8;
      *(short8*)lds_at(qs, r, cg, 256) =
          *(const short8*)(qb + (size_t)(bb*NT + csg + r)*NQK + hh*NHK + cg);
    }
    __syncthreads();
    short8 qaraw[4], qag[4];
    float si = SCALE * expf(Gsf[csl + irow]);
    #pragma unroll
    for (int kk=0;kk<4;kk++){
      short8 a = *(short8*)lds_at(qs, irow, kk*32 + (lane>>4)*8, 256);
      qaraw[kk] = a;
      short8 g;
      #pragma unroll
      for (int e=0;e<8;e++) g[e] = (short)f2bf(si * bf2f((unsigned short)a[e]));
      qag[kk] = g;
    }
    f32x4 oa[16];
    #pragma unroll
    for (int nt=0;nt<16;nt++) oa[nt] = (f32x4){0.f,0.f,0.f,0.f};
    #pragma unroll
    for (int nt=0;nt<16;nt++)
      #pragma unroll
      for (int kk=0;kk<4;kk++){
        short8 b = *(short8*)lds_at(STl, nt*16 + (lane&15), kk*32 + (lane>>4)*8, 256);
        oa[nt] = __builtin_amdgcn_mfma_f32_16x16x32_bf16(qag[kk], b, oa[nt], 0,0,0);
      }
    for (int jc=0; jc<=c; ++jc){
      int jsl = jc*64, jsg = t0 + jsl;
      __syncthreads();
      #pragma unroll
      for (int it=0; it<4; ++it){
        int task = it*256 + tid;
        int r = task >> 4, cg = (task & 15)*8;
        *(short8*)lds_at(ks, r, cg, 256) =
            *(const short8*)(kb + (size_t)(bb*NT + jsg + r)*NQK + hh*NHK + cg);
      }
      #pragma unroll
      for (int it=0; it<8; ++it){
        int task = it*256 + tid;
        int j = task & 63, ng = task >> 6;
        short8 vv = *(const short8*)(vb + (size_t)(bb*NT + jsg + j)*NV + hh*NHV + ng*8);
        #pragma unroll
        for (int e=0;e<8;e++)
          *(unsigned short*)lds_at(vT, ng*8+e, j, 128) = (unsigned short)vv[e];
      }
      __syncthreads();
      f32x4 pa[4];
      #pragma unroll
      for (int jt=0;jt<4;jt++) pa[jt] = (f32x4){0.f,0.f,0.f,0.f};
      #pragma unroll
      for (int jt=0;jt<4;jt++)
        #pragma unroll
        for (int kk=0;kk<4;kk++){
          short8 b = *(short8*)lds_at(ks, jt*16 + (lane&15), kk*32 + (lane>>4)*8, 256);
          pa[jt] = __builtin_amdgcn_mfma_f32_16x16x32_bf16(qaraw[kk], b, pa[jt], 0,0,0);
        }
      #pragma unroll
      for (int jt=0;jt<4;jt++)
        #pragma unroll
        for (int r=0;r<4;r++){
          int il = csl + 16*w + (lane>>4)*4 + r;
          int jl = jsl + jt*16 + (lane&15);
          float wgt = (jl <= il) ? SCALE * expf(Gsf[il] - Gsf[jl]) : 0.f;
          *(unsigned short*)lds_at(scp, 16*w + (lane>>4)*4 + r, jt*16 + (lane&15), 128)
              = f2bf(wgt * pa[jt][r]);
        }
      __syncthreads();
      short8 sa2[2];
      #pragma unroll
      for (int kk=0;kk<2;kk++)
        sa2[kk] = *(short8*)lds_at(scp, irow, kk*32 + (lane>>4)*8, 128);
      #pragma unroll
      for (int nt=0;nt<16;nt++)
        #pragma unroll
        for (int kk=0;kk<2;kk++){
          short8 b = *(short8*)lds_at(vT, nt*16 + (lane&15), kk*32 + (lane>>4)*8, 128);
          oa[nt] = __builtin_amdgcn_mfma_f32_16x16x32_bf16(sa2[kk], b, oa[nt], 0,0,0);
        }
    }
    float p4[4] = {0.f,0.f,0.f,0.f};
    #pragma unroll
    for (int nt=0;nt<16;nt++)
      #pragma unroll
      for (int r=0;r<4;r++) p4[r] += oa[nt][r]*oa[nt][r];
    #pragma unroll
    for (int r=0;r<4;r++){
      #pragma unroll
      for (int off=1; off<16; off<<=1) p4[r] += __shfl_xor(p4[r], off, 16);
    }
    float fr[4];
    #pragma unroll
    for (int r=0;r<4;r++) fr[r] = rsqrtf(p4[r]*(1.f/256.f) + 1e-5f);
    #pragma unroll
    for (int nt=0;nt<16;nt++)
      #pragma unroll
      for (int r=0;r<4;r++){
        int tg = csg + 16*w + (lane>>4)*4 + r;
        int n = nt*16 + (lane&15);
        size_t gidx = (size_t)(bb*NT + tg)*NV + hh*NHV + n;
        float gv = bf2f(gb[gidx]);
        float sw = gv / (1.f + expf(-gv));
        o2[gidx] = f2bf(oa[nt][r] * fr[r] * rms_s[n] * sw);
      }
  }
}

// ---------------- launch ----------------
extern "C" void kernel_launch(void* const* d_in, const int* in_sizes, int n_in,
                              void* d_out, int out_size, void* d_ws, size_t ws_size,
                              hipStream_t stream) {
  (void)in_sizes; (void)n_in; (void)out_size;
  const float* hs  = (const float*)d_in[0];
  const float* Wq  = (const float*)d_in[1];
  const float* Wk  = (const float*)d_in[2];
  const float* Wv  = (const float*)d_in[3];
  const float* Wa  = (const float*)d_in[4];
  const float* Wg  = (const float*)d_in[5];
  const float* Wo  = (const float*)d_in[6];
  const float* Al  = (const float*)d_in[7];
  const float* dtb = (const float*)d_in[8];
  const float* rmsw= (const float*)d_in[9];
  char* ws = (char*)d_ws;

  // workspace layout — total exactly 176,947,200 B (known-safe)
  constexpr size_t MB = 1048576;
  constexpr size_t OFF_Q    = 0;            // 16MB bf16 q
  constexpr size_t OFF_K    = 16*MB;        // 16MB bf16 k
  constexpr size_t OFF_V    = 32*MB;        // 32MB bf16 v
  constexpr size_t OFF_G    = 64*MB;        // 32MB bf16 gate
  constexpr size_t OFF_WQH  = 96*MB;
  constexpr size_t OFF_WQL  = 97*MB;
  constexpr size_t OFF_WKH  = 98*MB;
  constexpr size_t OFF_WKL  = 99*MB;
  constexpr size_t OFF_WV   = 100*MB;
  constexpr size_t OFF_WG   = 102*MB;
  constexpr size_t OFF_GC   = 104*MB;
  constexpr size_t OFF_GD   = 104*MB + 262144;
  constexpr size_t OFF_SB   = 104*MB + 786432;      // 32MB: hs_hi during projections, then S^T states, then wot
  constexpr size_t OFF_O2   = OFF_SB + 32*MB;       // 32MB: hs_lo during projections, then bf16 o2
  constexpr size_t WS_REQUIRED = OFF_O2 + 32*MB;    // = 176,947,200
  if (ws_size < WS_REQUIRED) return;

  unsigned short* qb  = (unsigned short*)(ws + OFF_Q);
  unsigned short* kb  = (unsigned short*)(ws + OFF_K);
  unsigned short* vb  = (unsigned short*)(ws + OFF_V);
  unsigned short* gb  = (unsigned short*)(ws + OFF_G);
  unsigned short* wqh = (unsigned short*)(ws + OFF_WQH);
  unsigned short* wql = (unsigned short*)(ws + OFF_WQL);
  unsigned short* wkh = (unsigned short*)(ws + OFF_WKH);
  unsigned short* wkl = (unsigned short*)(ws + OFF_WKL);
  unsigned short* wvt = (unsigned short*)(ws + OFF_WV);
  unsigned short* wgt = (unsigned short*)(ws + OFF_WG);
  float* Gc   = (float*)(ws + OFF_GC);
  double* Gd  = (double*)(ws + OFF_GD);
  float* Sb   = (float*)(ws + OFF_SB);
  unsigned short* hsh = (unsigned short*)(ws + OFF_SB);   // alias: hs_hi (dead before phaseA)
  unsigned short* hsl = (unsigned short*)(ws + OFF_O2);   // alias: hs_lo (dead before phaseC)
  unsigned short* wot = (unsigned short*)(ws + OFF_SB);   // alias: Sb dead after phaseC
  unsigned short* o2  = (unsigned short*)(ws + OFF_O2);

  // hs hi/lo split (once) + weight transposes
  k_split<<<8192, 256, 0, stream>>>(hs, hsh, hsl, NB*NT*ND);
  k_tc2<<<2048, 256, 0, stream>>>(Wq, wqh, wql, 1024, 512);
  k_tc2<<<2048, 256, 0, stream>>>(Wk, wkh, wkl, 1024, 512);
  k_tc <<<4096, 256, 0, stream>>>(Wv, wvt, 1024, 1024);
  k_tc <<<4096, 256, 0, stream>>>(Wg, wgt, 1024, 1024);

  // projections (A = hs_hi + hs_lo, bf16 staged)
  k_gemm2<1><<<dim3(128,4), 256, 0, stream>>>(hsh, hsl, wqh, wql, qb, 16384, 512, 1024);
  k_gemm2<1><<<dim3(128,4), 256, 0, stream>>>(hsh, hsl, wkh, wkl, kb, 16384, 512, 1024);
  k_gemm2<0><<<dim3(128,8), 256, 0, stream>>>(hsh, hsl, wvt, nullptr, vb, 16384, 1024, 1024);
  k_gemm2<0><<<dim3(128,8), 256, 0, stream>>>(hsh, hsl, wgt, nullptr, gb, 16384, 1024, 1024);

  k_alpha<<<16384, 256, 0, stream>>>(hs, Wa, Al, dtb, Gc);
  k_cumsum<<<8, 256, 0, stream>>>(Gc, Gd);

  k_phaseA<<<dim3(NBLK,8), 256, 0, stream>>>(kb, vb, Gd, Sb);
  k_phaseB<<<dim3(32,8), 256, 0, stream>>>(Sb, Gd);

  constexpr int PHC_LDS = (8192+8192+16384+32768+4096)*2 + 256*4 + 256*4;  // 141,312 B
  hipFuncSetAttribute(reinterpret_cast<const void*>(k_phaseC),
                      hipFuncAttributeMaxDynamicSharedMemorySize, PHC_LDS);
  k_phaseC<<<dim3(NBLK,8), 256, PHC_LDS, stream>>>(qb, kb, vb, gb, rmsw, Gd, Sb, o2);

  // Wo transpose into Sb alias (Sb dead now), then final GEMM
  k_tc<<<4096, 256, 0, stream>>>(Wo, wot, 1024, 1024);
  k_gemm<<<dim3(128,8), 256, 0, stream>>>(o2, wot, (float*)d_out, 16384, 1024, 1024);
}